// Round 1
// baseline (1592.213 us; speedup 1.0000x reference)
//
#include <hip/hip_runtime.h>
#include <hip/hip_bf16.h>
#include <math.h>

#define M_TOTAL 16384   // B*S = 4*4096
#define D_MODEL 1024
#define N_QKV   3072
#define NHEADS  16
#define HDIM    64
#define CURV    0.15f
#define EPS_F   1e-6f

// ---------------------------------------------------------------------------
// fp32 GEMM with bias: C[M][N] = A[M][K] @ W[K][N] + bias[N]
// 128x128 tile, BK=16, 256 threads, 8x8 micro-tile per thread.
// ---------------------------------------------------------------------------
__global__ __launch_bounds__(256)
void gemm_bias_f32(const float* __restrict__ A, const float* __restrict__ W,
                   const float* __restrict__ bias, float* __restrict__ C,
                   int M, int N, int K)
{
    const int BK = 16;
    __shared__ float As[16][132];   // [k][m], pad 132 to break conflicts
    __shared__ float Bs[16][132];   // [k][n]

    const int t  = threadIdx.x;
    const int tx = t & 15;          // n direction
    const int ty = t >> 4;          // m direction
    const int bm0 = blockIdx.y * 128;
    const int bn0 = blockIdx.x * 128;

    float acc[8][8];
    #pragma unroll
    for (int i = 0; i < 8; ++i)
        #pragma unroll
        for (int j = 0; j < 8; ++j) acc[i][j] = 0.f;

    // staging index precompute
    const int ai = t >> 2;          // 0..63 : A tile row (and +64)
    const int aj = (t & 3) * 4;     // k col group of 4
    const int br = t >> 4;          // 0..15 : W tile k row
    const int bc = (t & 15) * 4;    // n col group of 4 (and +64)

    for (int kt = 0; kt < K; kt += BK) {
        // ---- global loads into registers (overlap with previous compute) ----
        const float* Ap = A + (size_t)(bm0 + ai) * K + kt + aj;
        float4 a0 = *(const float4*)Ap;
        float4 a1 = *(const float4*)(Ap + (size_t)64 * K);
        const float* Wp = W + (size_t)(kt + br) * N + bn0 + bc;
        float4 b0 = *(const float4*)Wp;
        float4 b1 = *(const float4*)(Wp + 64);

        __syncthreads();   // previous iteration's LDS reads complete
        // A stored transposed: As[k][m]
        As[aj+0][ai] = a0.x; As[aj+1][ai] = a0.y;
        As[aj+2][ai] = a0.z; As[aj+3][ai] = a0.w;
        As[aj+0][ai+64] = a1.x; As[aj+1][ai+64] = a1.y;
        As[aj+2][ai+64] = a1.z; As[aj+3][ai+64] = a1.w;
        *(float4*)&Bs[br][bc]      = b0;
        *(float4*)&Bs[br][bc + 64] = b1;
        __syncthreads();

        #pragma unroll
        for (int kk = 0; kk < BK; ++kk) {
            float4 af0 = *(const float4*)&As[kk][ty*8];
            float4 af1 = *(const float4*)&As[kk][ty*8 + 4];
            float4 bf0 = *(const float4*)&Bs[kk][tx*8];
            float4 bf1 = *(const float4*)&Bs[kk][tx*8 + 4];
            float a_[8] = {af0.x,af0.y,af0.z,af0.w, af1.x,af1.y,af1.z,af1.w};
            float b_[8] = {bf0.x,bf0.y,bf0.z,bf0.w, bf1.x,bf1.y,bf1.z,bf1.w};
            #pragma unroll
            for (int i = 0; i < 8; ++i)
                #pragma unroll
                for (int j = 0; j < 8; ++j)
                    acc[i][j] = fmaf(a_[i], b_[j], acc[i][j]);
        }
    }

    // ---- epilogue: bias + store ----
    const int row0 = bm0 + ty*8;
    const int col0 = bn0 + tx*8;
    float bv[8];
    #pragma unroll
    for (int j = 0; j < 8; ++j) bv[j] = bias[col0 + j];
    #pragma unroll
    for (int i = 0; i < 8; ++i) {
        float* Cp = C + (size_t)(row0 + i) * N + col0;
        float4 o0 = make_float4(acc[i][0]+bv[0], acc[i][1]+bv[1],
                                acc[i][2]+bv[2], acc[i][3]+bv[3]);
        float4 o1 = make_float4(acc[i][4]+bv[4], acc[i][5]+bv[5],
                                acc[i][6]+bv[6], acc[i][7]+bv[7]);
        *(float4*)Cp       = o0;
        *((float4*)Cp + 1) = o1;
    }
}

// ---------------------------------------------------------------------------
// Per-position head attention. One block (256 threads) per sequence position.
// qkv row layout: [3][16][64]  (q | k | v), each 16 heads x 64 dims.
// thread t = (h,g) pair: h = t>>4, g = t&15.
// ---------------------------------------------------------------------------
__global__ __launch_bounds__(256)
void attn_heads_kernel(const float* __restrict__ qkv, float* __restrict__ aout)
{
    __shared__ float qs[16][68], ks[16][68], vs[16][68];  // pad 68: float4-aligned
    __shared__ float qsq[16], ksq[16];
    __shared__ float attn_s[16][17];

    const int p = blockIdx.x;
    const int t = threadIdx.x;
    const float* row = qkv + (size_t)p * N_QKV;

    // stage 3072 floats = 768 float4 (3 per thread)
    for (int i = t; i < N_QKV/4; i += 256) {
        float4 val = ((const float4*)row)[i];
        int e   = i << 2;
        int sec = e >> 10;          // 0=q 1=k 2=v
        int h   = (e >> 6) & 15;
        int d   = e & 63;
        float* dst = (sec == 0) ? &qs[h][d] : (sec == 1) ? &ks[h][d] : &vs[h][d];
        *(float4*)dst = val;
    }
    __syncthreads();

    // q_sq / k_sq by threads 0..31
    if (t < 32) {
        int hh = t & 15;
        const float* src = (t < 16) ? qs[hh] : ks[hh];
        float s = 0.f;
        #pragma unroll
        for (int d0 = 0; d0 < 64; d0 += 4) {
            float4 u = *(const float4*)(src + d0);
            s = fmaf(u.x,u.x, fmaf(u.y,u.y, fmaf(u.z,u.z, fmaf(u.w,u.w, s))));
        }
        if (t < 16) qsq[hh] = s; else ksq[hh] = s;
    }

    // qk dot for this thread's (h,g) pair
    const int h = t >> 4;
    const int g = t & 15;
    float dot = 0.f;
    {
        const float* qr = qs[h];
        const float* kr = ks[g];
        #pragma unroll
        for (int d0 = 0; d0 < 64; d0 += 4) {
            float4 a = *(const float4*)(qr + d0);
            float4 b = *(const float4*)(kr + d0);
            dot = fmaf(a.x,b.x, fmaf(a.y,b.y, fmaf(a.z,b.z, fmaf(a.w,b.w, dot))));
        }
    }
    __syncthreads();   // qsq/ksq visible

    float dsq = fmaxf(qsq[h] + ksq[g] - 2.f * dot, 0.f);
    dsq = dsq * (1.f + CURV * cosf(sqrtf(dsq + EPS_F)));
    float force = sqrtf(qsq[h]) * sqrtf(ksq[g]) / (dsq + EPS_F);

    // softmax over g: 16-lane-group reductions (g lives in lane bits [3:0])
    float m = force;
    #pragma unroll
    for (int off = 8; off >= 1; off >>= 1)
        m = fmaxf(m, __shfl_xor(m, off, 16));
    float e = expf(force - m);
    float ssum = e;
    #pragma unroll
    for (int off = 8; off >= 1; off >>= 1)
        ssum += __shfl_xor(ssum, off, 16);
    attn_s[h][g] = e / ssum;
    __syncthreads();

    // out[h][d] = sum_g attn[h][g] * v[g][d];  thread: d = t&63, 4 h's
    const int d  = t & 63;
    const int hb = t >> 6;
    float o[4] = {0.f, 0.f, 0.f, 0.f};
    #pragma unroll
    for (int gg = 0; gg < 16; ++gg) {
        float vv = vs[gg][d];
        #pragma unroll
        for (int hh = 0; hh < 4; ++hh)
            o[hh] = fmaf(attn_s[hb + hh*4][gg], vv, o[hh]);
    }
    float* orow = aout + (size_t)p * D_MODEL;
    #pragma unroll
    for (int hh = 0; hh < 4; ++hh)
        orow[(hb + hh*4) * HDIM + d] = o[hh];
}

// ---------------------------------------------------------------------------
extern "C" void kernel_launch(void* const* d_in, const int* in_sizes, int n_in,
                              void* d_out, int out_size, void* d_ws, size_t ws_size,
                              hipStream_t stream)
{
    const float* x     = (const float*)d_in[0];   // 16384 x 1024
    const float* W_qkv = (const float*)d_in[1];   // 1024 x 3072
    const float* b_qkv = (const float*)d_in[2];   // 3072
    const float* W_out = (const float*)d_in[3];   // 1024 x 1024
    const float* b_out = (const float*)d_in[4];   // 1024
    float* out = (float*)d_out;                   // 16384 x 1024

    float* qkv      = (float*)d_ws;                         // 16384*3072 f32 (192 MB)
    float* attn_out = qkv + (size_t)M_TOTAL * N_QKV;        // 16384*1024 f32 (64 MB)

    // 1) qkv = x @ W_qkv + b_qkv
    dim3 g1(N_QKV / 128, M_TOTAL / 128);
    gemm_bias_f32<<<g1, 256, 0, stream>>>(x, W_qkv, b_qkv, qkv,
                                          M_TOTAL, N_QKV, D_MODEL);

    // 2) per-position head attention
    attn_heads_kernel<<<M_TOTAL, 256, 0, stream>>>(qkv, attn_out);

    // 3) out = attn_out @ W_out + b_out
    dim3 g2(D_MODEL / 128, M_TOTAL / 128);
    gemm_bias_f32<<<g2, 256, 0, stream>>>(attn_out, W_out, b_out, out,
                                          M_TOTAL, D_MODEL, D_MODEL);
}

// Round 2
// 293.148 us; speedup vs baseline: 5.4314x; 5.4314x over previous
//
#include <hip/hip_runtime.h>
#include <hip/hip_bf16.h>
#include <math.h>

#define M_TOTAL 16384   // B*S = 4*4096
#define D_MODEL 1024
#define N_QKV   3072
#define NHEADS  16
#define HDIM    64
#define CURV    0.15f
#define EPS_F   1e-6f

typedef __attribute__((ext_vector_type(8))) short short8v;
typedef __attribute__((ext_vector_type(4))) float f32x4;

__device__ __forceinline__ void gl_lds16(const void* g, void* l) {
    __builtin_amdgcn_global_load_lds(
        (const __attribute__((address_space(1))) void*)g,
        (__attribute__((address_space(3))) void*)l, 16, 0, 0);
}

__device__ __forceinline__ unsigned short f2bf_bits(float x) {
    __hip_bfloat16 t = __float2bfloat16(x);
    return *(unsigned short*)&t;
}

// ---------------------------------------------------------------------------
// cast fp32 -> bf16, 4 elems/thread
// ---------------------------------------------------------------------------
__global__ __launch_bounds__(256)
void cast_f32_bf16(const float* __restrict__ in, unsigned short* __restrict__ out,
                   int ngroups)   // ngroups = n/4
{
    int i = blockIdx.x * 256 + threadIdx.x;
    if (i >= ngroups) return;
    float4 u = ((const float4*)in)[i];
    ushort4 r;
    r.x = f2bf_bits(u.x); r.y = f2bf_bits(u.y);
    r.z = f2bf_bits(u.z); r.w = f2bf_bits(u.w);
    ((ushort4*)out)[i] = r;
}

// ---------------------------------------------------------------------------
// transpose + cast: W[K][N] fp32  ->  Wt[N][K] bf16.  32x32 LDS tile.
// ---------------------------------------------------------------------------
__global__ __launch_bounds__(256)
void transpose_cast(const float* __restrict__ W, unsigned short* __restrict__ Wt,
                    int K, int N)
{
    __shared__ float tile[32][33];
    const int n0 = blockIdx.x * 32;
    const int k0 = blockIdx.y * 32;
    const int tx = threadIdx.x & 31;
    const int ty = threadIdx.x >> 5;   // 0..7
    #pragma unroll
    for (int i = 0; i < 32; i += 8)
        tile[ty + i][tx] = W[(size_t)(k0 + ty + i) * N + n0 + tx];
    __syncthreads();
    #pragma unroll
    for (int i = 0; i < 32; i += 8)
        Wt[(size_t)(n0 + ty + i) * K + k0 + tx] = f2bf_bits(tile[tx][ty + i]);
}

// ---------------------------------------------------------------------------
// bf16 MFMA GEMM: C[M][N] = A[M][K] @ Bt[N][K]^T + bias[N]   (fp32 out)
// m97 structure: 128x128 tile, BK=32, 4 waves, 4x4 16x16x32 fragments/wave,
// global_load_lds width-16 staging, single LDS buffer, 2 barriers/K-step.
// ---------------------------------------------------------------------------
__global__ __launch_bounds__(256)
void gemm_mfma_bf16(const unsigned short* __restrict__ A,   // [M][K] bf16 bits
                    const unsigned short* __restrict__ Bt,  // [N][K] bf16 bits
                    const float* __restrict__ bias,
                    float* __restrict__ C,
                    int M, int N, int K)
{
    __shared__ short As[128 * 32];
    __shared__ short Bs[128 * 32];

    const int t    = threadIdx.x;
    const int bm0  = blockIdx.y * 128;
    const int bn0  = blockIdx.x * 128;
    const int wid  = t >> 6;
    const int lane = t & 63;
    const int wr   = (wid >> 1) * 64;   // wave row offset in tile
    const int wc   = (wid & 1) * 64;    // wave col offset in tile
    const int lr   = lane & 15;
    const int lk   = (lane >> 4) * 8;   // k element offset within BK

    f32x4 acc[4][4] = {};

    // staging: thread t covers LDS shorts [t*8, t*8+8) per call; 2 calls each
    const int sr = t >> 2;              // 0..63  (row within 64-row half)
    const int sc = (t & 3) * 8;         // k element offset
    const unsigned short* Ag = A  + (size_t)(bm0 + sr) * K + sc;
    const unsigned short* Bg = Bt + (size_t)(bn0 + sr) * K + sc;
    short* AsD = As + t * 8;
    short* BsD = Bs + t * 8;

    for (int kt = 0; kt < K; kt += 32) {
        gl_lds16(Ag + kt,                   AsD);
        gl_lds16(Ag + (size_t)64 * K + kt,  AsD + 2048);
        gl_lds16(Bg + kt,                   BsD);
        gl_lds16(Bg + (size_t)64 * K + kt,  BsD + 2048);
        __syncthreads();   // drains vmcnt (global_load_lds) + makes LDS visible

        short8v a[4], b[4];
        #pragma unroll
        for (int m = 0; m < 4; ++m)
            a[m] = *(const short8v*)&As[(wr + m * 16 + lr) * 32 + lk];
        #pragma unroll
        for (int n = 0; n < 4; ++n)
            b[n] = *(const short8v*)&Bs[(wc + n * 16 + lr) * 32 + lk];

        #pragma unroll
        for (int m = 0; m < 4; ++m)
            #pragma unroll
            for (int n = 0; n < 4; ++n)
                acc[m][n] = __builtin_amdgcn_mfma_f32_16x16x32_bf16(
                                a[m], b[n], acc[m][n], 0, 0, 0);
        __syncthreads();   // LDS reads done before next stage overwrites
    }

    // epilogue: C/D layout col=lane&15, row=(lane>>4)*4+reg  [verified m89/m91]
    const int crow = wr + (lane >> 4) * 4;
    const int ccol = wc + lr;
    #pragma unroll
    for (int m = 0; m < 4; ++m) {
        #pragma unroll
        for (int j = 0; j < 4; ++j) {
            const int r = bm0 + crow + m * 16 + j;
            float* Cp = C + (size_t)r * N;
            #pragma unroll
            for (int n = 0; n < 4; ++n) {
                const int c = bn0 + ccol + n * 16;
                Cp[c] = acc[m][n][j] + bias[c];
            }
        }
    }
}

// ---------------------------------------------------------------------------
// Per-position head attention (fp32 in, bf16 out). One block per position.
// qkv row layout: [3][16][64]. thread t = (h,g) pair.
// ---------------------------------------------------------------------------
__global__ __launch_bounds__(256)
void attn_heads_kernel(const float* __restrict__ qkv, unsigned short* __restrict__ aout)
{
    __shared__ float qs[16][68], ks[16][68], vs[16][68];
    __shared__ float qsq[16], ksq[16];
    __shared__ float attn_s[16][17];

    const int p = blockIdx.x;
    const int t = threadIdx.x;
    const float* row = qkv + (size_t)p * N_QKV;

    for (int i = t; i < N_QKV / 4; i += 256) {
        float4 val = ((const float4*)row)[i];
        int e   = i << 2;
        int sec = e >> 10;
        int h   = (e >> 6) & 15;
        int d   = e & 63;
        float* dst = (sec == 0) ? &qs[h][d] : (sec == 1) ? &ks[h][d] : &vs[h][d];
        *(float4*)dst = val;
    }
    __syncthreads();

    if (t < 32) {
        int hh = t & 15;
        const float* src = (t < 16) ? qs[hh] : ks[hh];
        float s = 0.f;
        #pragma unroll
        for (int d0 = 0; d0 < 64; d0 += 4) {
            float4 u = *(const float4*)(src + d0);
            s = fmaf(u.x,u.x, fmaf(u.y,u.y, fmaf(u.z,u.z, fmaf(u.w,u.w, s))));
        }
        if (t < 16) qsq[hh] = s; else ksq[hh] = s;
    }

    const int h = t >> 4;
    const int g = t & 15;
    float dot = 0.f;
    {
        const float* qr = qs[h];
        const float* kr = ks[g];
        #pragma unroll
        for (int d0 = 0; d0 < 64; d0 += 4) {
            float4 a = *(const float4*)(qr + d0);
            float4 b = *(const float4*)(kr + d0);
            dot = fmaf(a.x,b.x, fmaf(a.y,b.y, fmaf(a.z,b.z, fmaf(a.w,b.w, dot))));
        }
    }
    __syncthreads();

    float dsq = fmaxf(qsq[h] + ksq[g] - 2.f * dot, 0.f);
    dsq = dsq * (1.f + CURV * cosf(sqrtf(dsq + EPS_F)));
    float force = sqrtf(qsq[h]) * sqrtf(ksq[g]) / (dsq + EPS_F);

    float m = force;
    #pragma unroll
    for (int off = 8; off >= 1; off >>= 1)
        m = fmaxf(m, __shfl_xor(m, off, 16));
    float e = expf(force - m);
    float ssum = e;
    #pragma unroll
    for (int off = 8; off >= 1; off >>= 1)
        ssum += __shfl_xor(ssum, off, 16);
    attn_s[h][g] = e / ssum;
    __syncthreads();

    const int d  = t & 63;
    const int hb = t >> 6;
    float o[4] = {0.f, 0.f, 0.f, 0.f};
    #pragma unroll
    for (int gg = 0; gg < 16; ++gg) {
        float vv = vs[gg][d];
        #pragma unroll
        for (int hh = 0; hh < 4; ++hh)
            o[hh] = fmaf(attn_s[hb + hh*4][gg], vv, o[hh]);
    }
    unsigned short* orow = aout + (size_t)p * D_MODEL;
    #pragma unroll
    for (int hh = 0; hh < 4; ++hh)
        orow[(hb + hh*4) * HDIM + d] = f2bf_bits(o[hh]);
}

// ---------------------------------------------------------------------------
extern "C" void kernel_launch(void* const* d_in, const int* in_sizes, int n_in,
                              void* d_out, int out_size, void* d_ws, size_t ws_size,
                              hipStream_t stream)
{
    const float* x     = (const float*)d_in[0];   // 16384 x 1024
    const float* W_qkv = (const float*)d_in[1];   // 1024 x 3072
    const float* b_qkv = (const float*)d_in[2];   // 3072
    const float* W_out = (const float*)d_in[3];   // 1024 x 1024
    const float* b_out = (const float*)d_in[4];   // 1024
    float* out = (float*)d_out;                   // 16384 x 1024

    // workspace layout (bytes):
    //   [0, 192MB)         qkv fp32 (16384*3072)
    //   [192MB, 224MB)     xb bf16  (16384*1024)  -- aliased by attn_out after GEMM1
    //   [224MB, 230MB)     Wt_qkv bf16 (3072*1024)
    //   [230MB, 232MB)     Wt_out bf16 (1024*1024)
    char* ws = (char*)d_ws;
    float*          qkv = (float*)ws;
    unsigned short* xb  = (unsigned short*)(ws + (size_t)M_TOTAL * N_QKV * 4);
    unsigned short* ab  = xb;   // alias: xb dead after GEMM1
    unsigned short* Wt1 = (unsigned short*)(ws + (size_t)M_TOTAL * N_QKV * 4
                                               + (size_t)M_TOTAL * D_MODEL * 2);
    unsigned short* Wt2 = Wt1 + (size_t)N_QKV * D_MODEL;

    // 0a) cast x -> bf16
    {
        int ngroups = M_TOTAL * D_MODEL / 4;
        cast_f32_bf16<<<ngroups / 256, 256, 0, stream>>>(x, xb, ngroups);
    }
    // 0b) transpose+cast weights
    {
        dim3 g(N_QKV / 32, D_MODEL / 32);
        transpose_cast<<<g, 256, 0, stream>>>(W_qkv, Wt1, D_MODEL, N_QKV);
        dim3 g2(D_MODEL / 32, D_MODEL / 32);
        transpose_cast<<<g2, 256, 0, stream>>>(W_out, Wt2, D_MODEL, D_MODEL);
    }

    // 1) qkv = x @ W_qkv + b_qkv   (bf16 MFMA, fp32 out)
    {
        dim3 g(N_QKV / 128, M_TOTAL / 128);
        gemm_mfma_bf16<<<g, 256, 0, stream>>>(xb, Wt1, b_qkv, qkv,
                                              M_TOTAL, N_QKV, D_MODEL);
    }

    // 2) per-position head attention (writes bf16)
    attn_heads_kernel<<<M_TOTAL, 256, 0, stream>>>(qkv, ab);

    // 3) out = attn_out @ W_out + b_out
    {
        dim3 g(D_MODEL / 128, M_TOTAL / 128);
        gemm_mfma_bf16<<<g, 256, 0, stream>>>(ab, Wt2, b_out, out,
                                              M_TOTAL, D_MODEL, D_MODEL);
    }
}

// Round 3
// 224.938 us; speedup vs baseline: 7.0785x; 1.3032x over previous
//
#include <hip/hip_runtime.h>
#include <hip/hip_bf16.h>
#include <math.h>

#define M_TOTAL 16384   // B*S = 4*4096
#define D_MODEL 1024
#define N_QKV   3072
#define CURV    0.15f
#define EPS_F   1e-6f

typedef __attribute__((ext_vector_type(8))) short short8v;
typedef __attribute__((ext_vector_type(4))) float f32x4;

__device__ __forceinline__ void gl_lds16(const void* g, void* l) {
    __builtin_amdgcn_global_load_lds(
        (const __attribute__((address_space(1))) void*)g,
        (__attribute__((address_space(3))) void*)l, 16, 0, 0);
}
__device__ __forceinline__ unsigned short f2bf_bits(float x) {
    __hip_bfloat16 t = __float2bfloat16(x);
    return *(unsigned short*)&t;
}
__device__ __forceinline__ float bf2f(unsigned short u) {
    return __uint_as_float(((unsigned)u) << 16);
}

// ---------------------------------------------------------------------------
// cast fp32 -> bf16, 4 elems/thread
// ---------------------------------------------------------------------------
__global__ __launch_bounds__(256)
void cast_f32_bf16(const float* __restrict__ in, unsigned short* __restrict__ out,
                   int ngroups)
{
    int i = blockIdx.x * 256 + threadIdx.x;
    if (i >= ngroups) return;
    float4 u = ((const float4*)in)[i];
    ushort4 r;
    r.x = f2bf_bits(u.x); r.y = f2bf_bits(u.y);
    r.z = f2bf_bits(u.z); r.w = f2bf_bits(u.w);
    ((ushort4*)out)[i] = r;
}

// ---------------------------------------------------------------------------
// transpose + cast: W[K][N] fp32  ->  Wt[N][K] bf16.
// ---------------------------------------------------------------------------
__global__ __launch_bounds__(256)
void transpose_cast(const float* __restrict__ W, unsigned short* __restrict__ Wt,
                    int K, int N)
{
    __shared__ float tile[32][33];
    const int n0 = blockIdx.x * 32;
    const int k0 = blockIdx.y * 32;
    const int tx = threadIdx.x & 31;
    const int ty = threadIdx.x >> 5;
    #pragma unroll
    for (int i = 0; i < 32; i += 8)
        tile[ty + i][tx] = W[(size_t)(k0 + ty + i) * N + n0 + tx];
    __syncthreads();
    #pragma unroll
    for (int i = 0; i < 32; i += 8)
        Wt[(size_t)(n0 + ty + i) * K + k0 + tx] = f2bf_bits(tile[tx][ty + i]);
}

// ---------------------------------------------------------------------------
// 256x256 8-phase bf16 MFMA GEMM (m201-style): C = A[M][K] @ Bt[N][K]^T + bias
// 512 threads = 8 waves (2M x 4N); BK=64; 128 KiB LDS double buffer;
// XOR swizzle (chunk ^= row&7) via pre-swizzled source + swizzled ds_read;
// counted vmcnt(6) at tile boundaries (3 half-tiles in flight); setprio on MFMA.
// Stage stream per tile T: p0:B1(T+1) p1:A0(T+2) p2:A1(T+2) p3:B0(T+2).
// Slot-free analysis: A slots read only at p0 (a-all), B at p0/p1 -> no clobber.
// ---------------------------------------------------------------------------
template<int OUT_BF16>
__global__ __launch_bounds__(512, 2)
void gemm256_8ph(const unsigned short* __restrict__ A,
                 const unsigned short* __restrict__ Bt,
                 const float* __restrict__ bias,
                 void* __restrict__ Cout,
                 int M, int N, int K, int nbx)
{
    __shared__ __align__(16) short smem_s[65536];   // 128 KiB

    const int t    = threadIdx.x;
    const int w    = t >> 6;
    const int lane = t & 63;
    const int wm   = w >> 2;          // 0..1
    const int wn   = w & 3;           // 0..3
    const int lr   = lane & 15;
    const int hi   = lane >> 4;       // 0..3
    const int lo7  = lane & 7;

    // bijective XCD chunk swizzle (gridDim.x % 8 == 0)
    const int nwg  = gridDim.x;
    const int orig = blockIdx.x;
    const int wgid = (orig & 7) * (nwg >> 3) + (orig >> 3);
    const int by = wgid / nbx, bx = wgid % nbx;
    const int bm0 = by * 256, bn0 = bx * 256;

    const int nt = K >> 6;            // = 16 for K=1024

    // staging geometry: thread t covers chunk c = t (+512 for 2nd call) of a
    // 128row x 8chunk half-tile; LDS dest linear, source col pre-swizzled.
    const int srow = t >> 3;                        // 0..63
    const int scol = ((t & 7) ^ (srow & 7)) * 8;    // swizzled element col
    const unsigned short* Ag = A  + (size_t)(bm0 + srow) * K + scol;
    const unsigned short* Bg = Bt + (size_t)(bn0 + srow) * K + scol;
    const int wbase = w * 1024;                     // wave's byte base in half

    auto STAGE = [&](int which, int half, int tile) {
        const unsigned short* g0 = (which ? Bg : Ag)
                                 + (size_t)(half * 128) * K + (size_t)tile * 64;
        char* d0 = (char*)smem_s + ((tile & 1) * 65536 + which * 32768
                                    + half * 16384 + wbase);
        gl_lds16(g0,                d0);
        gl_lds16(g0 + (size_t)64*K, d0 + 8192);
    };

    short8v a[8][2], b[4][2];
    f32x4 acc[8][4] = {};

    auto LDA = [&](int buf, int m, int ks) {
        a[m][ks] = *(const short8v*)&smem_s[buf*32768 + wm*8192
                        + (m*16 + lr)*64 + (((ks*4 + hi) ^ lo7) * 8)];
    };
    auto LDB = [&](int buf, int n, int ks) {
        b[n][ks] = *(const short8v*)&smem_s[buf*32768 + 16384 + (wn>>1)*8192
                        + ((wn&1)*64 + n*16 + lr)*64 + (((ks*4 + hi) ^ lo7) * 8)];
    };
    auto QUAD = [&](int mlo, int nlo) {
        __builtin_amdgcn_s_setprio(1);
        #pragma unroll
        for (int mi = 0; mi < 4; ++mi)
            #pragma unroll
            for (int ni = 0; ni < 2; ++ni)
                #pragma unroll
                for (int ks = 0; ks < 2; ++ks)
                    acc[mlo+mi][nlo+ni] = __builtin_amdgcn_mfma_f32_16x16x32_bf16(
                        a[mlo+mi][ks], b[nlo+ni][ks], acc[mlo+mi][nlo+ni], 0, 0, 0);
        __builtin_amdgcn_s_setprio(0);
    };

    // ---- prologue: 7 half-tiles in stream order (tile0 all, tile1 A0 A1 B0)
    STAGE(0,0,0); STAGE(0,1,0); STAGE(1,0,0); STAGE(1,1,0);
    STAGE(0,0,1); STAGE(0,1,1); STAGE(1,0,1);
    asm volatile("s_waitcnt vmcnt(6)" ::: "memory");   // tile 0 resident
    __builtin_amdgcn_s_barrier();

    for (int T = 0; T < nt; ++T) {
        const int buf = T & 1;
        // ---- phase 0: read a-all + b[0..1]; MFMA Q(m0-3, n0-1) ----
        #pragma unroll
        for (int m = 0; m < 8; ++m) { LDA(buf,m,0); LDA(buf,m,1); }
        LDB(buf,0,0); LDB(buf,0,1); LDB(buf,1,0); LDB(buf,1,1);
        if (T+1 < nt) STAGE(1,1,T+1);
        __builtin_amdgcn_s_barrier();
        asm volatile("s_waitcnt lgkmcnt(0)" ::: "memory");
        __builtin_amdgcn_sched_barrier(0);
        QUAD(0,0);
        __builtin_amdgcn_s_barrier();
        // ---- phase 1: read b[2..3]; MFMA Q(m0-3, n2-3) ----
        LDB(buf,2,0); LDB(buf,2,1); LDB(buf,3,0); LDB(buf,3,1);
        if (T+2 < nt) STAGE(0,0,T+2);
        __builtin_amdgcn_s_barrier();
        asm volatile("s_waitcnt lgkmcnt(0)" ::: "memory");
        __builtin_amdgcn_sched_barrier(0);
        QUAD(0,2);
        __builtin_amdgcn_s_barrier();
        // ---- phase 2: MFMA Q(m4-7, n0-1) ----
        if (T+2 < nt) STAGE(0,1,T+2);
        __builtin_amdgcn_s_barrier();
        QUAD(4,0);
        __builtin_amdgcn_s_barrier();
        // ---- phase 3: MFMA Q(m4-7, n2-3); tile-boundary counted vmcnt ----
        if (T+2 < nt) STAGE(1,0,T+2);
        __builtin_amdgcn_s_barrier();
        QUAD(4,2);
        if (T+2 < nt) { asm volatile("s_waitcnt vmcnt(6)" ::: "memory"); }
        else          { asm volatile("s_waitcnt vmcnt(0)" ::: "memory"); }
        __builtin_amdgcn_s_barrier();
    }

    // ---- epilogue: C/D layout col=lane&15, row=hi*4+j ----
    const int r0 = bm0 + wm*128 + hi*4;
    const int cb = bn0 + wn*64 + lr;
    float bv[4];
    #pragma unroll
    for (int n = 0; n < 4; ++n) bv[n] = bias[cb + n*16];
    if (OUT_BF16) {
        unsigned short* Cb = (unsigned short*)Cout;
        #pragma unroll
        for (int m = 0; m < 8; ++m)
            #pragma unroll
            for (int j = 0; j < 4; ++j) {
                unsigned short* rp = Cb + (size_t)(r0 + m*16 + j) * N;
                #pragma unroll
                for (int n = 0; n < 4; ++n)
                    rp[cb + n*16] = f2bf_bits(acc[m][n][j] + bv[n]);
            }
    } else {
        float* Cf = (float*)Cout;
        #pragma unroll
        for (int m = 0; m < 8; ++m)
            #pragma unroll
            for (int j = 0; j < 4; ++j) {
                float* rp = Cf + (size_t)(r0 + m*16 + j) * N;
                #pragma unroll
                for (int n = 0; n < 4; ++n)
                    rp[cb + n*16] = acc[m][n][j] + bv[n];
            }
    }
}

// ---------------------------------------------------------------------------
// Per-position head attention (bf16 in, bf16 out). One block per position.
// qkv row layout: [3][16][64]. thread t = (h,g) pair. fp32 internal math.
// ---------------------------------------------------------------------------
__global__ __launch_bounds__(256)
void attn_heads_kernel(const unsigned short* __restrict__ qkv,
                       unsigned short* __restrict__ aout)
{
    __shared__ float qs[16][68], ks[16][68], vs[16][68];
    __shared__ float qsq[16], ksq[16];
    __shared__ float attn_s[16][17];

    const int p = blockIdx.x;
    const int t = threadIdx.x;
    const short8v* rowv = (const short8v*)(qkv + (size_t)p * N_QKV);

    // stage+convert: 384 chunks of 8 bf16
    for (int c = t; c < N_QKV / 8; c += 256) {
        short8v v = rowv[c];
        int e0  = c << 3;
        int sec = e0 >> 10;
        int h   = (e0 >> 6) & 15;
        int d   = e0 & 63;
        float* dst = (sec == 0) ? &qs[h][d] : (sec == 1) ? &ks[h][d] : &vs[h][d];
        #pragma unroll
        for (int i = 0; i < 8; ++i)
            dst[i] = bf2f((unsigned short)v[i]);
    }
    __syncthreads();

    if (t < 32) {
        int hh = t & 15;
        const float* src = (t < 16) ? qs[hh] : ks[hh];
        float s = 0.f;
        #pragma unroll
        for (int d0 = 0; d0 < 64; d0 += 4) {
            float4 u = *(const float4*)(src + d0);
            s = fmaf(u.x,u.x, fmaf(u.y,u.y, fmaf(u.z,u.z, fmaf(u.w,u.w, s))));
        }
        if (t < 16) qsq[hh] = s; else ksq[hh] = s;
    }

    const int h = t >> 4;
    const int g = t & 15;
    float dot = 0.f;
    {
        const float* qr = qs[h];
        const float* kr = ks[g];
        #pragma unroll
        for (int d0 = 0; d0 < 64; d0 += 4) {
            float4 a = *(const float4*)(qr + d0);
            float4 b = *(const float4*)(kr + d0);
            dot = fmaf(a.x,b.x, fmaf(a.y,b.y, fmaf(a.z,b.z, fmaf(a.w,b.w, dot))));
        }
    }
    __syncthreads();

    float dsq = fmaxf(qsq[h] + ksq[g] - 2.f * dot, 0.f);
    dsq = dsq * (1.f + CURV * cosf(sqrtf(dsq + EPS_F)));
    float force = sqrtf(qsq[h]) * sqrtf(ksq[g]) / (dsq + EPS_F);

    float m = force;
    #pragma unroll
    for (int off = 8; off >= 1; off >>= 1)
        m = fmaxf(m, __shfl_xor(m, off, 16));
    float e = expf(force - m);
    float ssum = e;
    #pragma unroll
    for (int off = 8; off >= 1; off >>= 1)
        ssum += __shfl_xor(ssum, off, 16);
    attn_s[h][g] = e / ssum;
    __syncthreads();

    const int d  = t & 63;
    const int hb = t >> 6;
    float o[4] = {0.f, 0.f, 0.f, 0.f};
    #pragma unroll
    for (int gg = 0; gg < 16; ++gg) {
        float vv = vs[gg][d];
        #pragma unroll
        for (int hh = 0; hh < 4; ++hh)
            o[hh] = fmaf(attn_s[hb + hh*4][gg], vv, o[hh]);
    }
    unsigned short* orow = aout + (size_t)p * D_MODEL;
    #pragma unroll
    for (int hh = 0; hh < 4; ++hh)
        orow[(hb + hh*4) * 64 + d] = f2bf_bits(o[hh]);
}

// ---------------------------------------------------------------------------
extern "C" void kernel_launch(void* const* d_in, const int* in_sizes, int n_in,
                              void* d_out, int out_size, void* d_ws, size_t ws_size,
                              hipStream_t stream)
{
    const float* x     = (const float*)d_in[0];   // 16384 x 1024
    const float* W_qkv = (const float*)d_in[1];   // 1024 x 3072
    const float* b_qkv = (const float*)d_in[2];   // 3072
    const float* W_out = (const float*)d_in[3];   // 1024 x 1024
    const float* b_out = (const float*)d_in[4];   // 1024
    float* out = (float*)d_out;                   // 16384 x 1024

    // workspace: [0,96M) qkv bf16 | [96M,128M) xb/ab bf16 | Wt1 6M | Wt2 2M
    char* ws = (char*)d_ws;
    unsigned short* qkvb = (unsigned short*)ws;
    unsigned short* xb   = (unsigned short*)(ws + (size_t)M_TOTAL * N_QKV * 2);
    unsigned short* ab   = xb;   // alias: xb dead after GEMM1
    unsigned short* Wt1  = (unsigned short*)(ws + (size_t)M_TOTAL * N_QKV * 2
                                                + (size_t)M_TOTAL * D_MODEL * 2);
    unsigned short* Wt2  = Wt1 + (size_t)N_QKV * D_MODEL;

    // 0a) cast x -> bf16
    {
        int ngroups = M_TOTAL * D_MODEL / 4;
        cast_f32_bf16<<<ngroups / 256, 256, 0, stream>>>(x, xb, ngroups);
    }
    // 0b) transpose+cast weights
    {
        dim3 g(N_QKV / 32, D_MODEL / 32);
        transpose_cast<<<g, 256, 0, stream>>>(W_qkv, Wt1, D_MODEL, N_QKV);
        dim3 g2(D_MODEL / 32, D_MODEL / 32);
        transpose_cast<<<g2, 256, 0, stream>>>(W_out, Wt2, D_MODEL, D_MODEL);
    }

    // 1) qkv = x @ W_qkv + b_qkv  (bf16 out)
    {
        int nbx = N_QKV / 256;                 // 12
        int nwg = (M_TOTAL / 256) * nbx;       // 768 (%8==0)
        gemm256_8ph<1><<<nwg, 512, 0, stream>>>(xb, Wt1, b_qkv, qkvb,
                                                M_TOTAL, N_QKV, D_MODEL, nbx);
    }

    // 2) per-position head attention (bf16 -> bf16)
    attn_heads_kernel<<<M_TOTAL, 256, 0, stream>>>(qkvb, ab);

    // 3) out = ab @ W_out + b_out  (fp32 out)
    {
        int nbx = D_MODEL / 256;               // 4
        int nwg = (M_TOTAL / 256) * nbx;       // 256 (%8==0)
        gemm256_8ph<0><<<nwg, 512, 0, stream>>>(ab, Wt2, b_out, out,
                                                M_TOTAL, D_MODEL, D_MODEL, nbx);
    }
}

// Round 4
// 222.644 us; speedup vs baseline: 7.1514x; 1.0103x over previous
//
#include <hip/hip_runtime.h>
#include <hip/hip_bf16.h>
#include <math.h>

#define M_TOTAL 16384   // B*S = 4*4096
#define D_MODEL 1024
#define N_QKV   3072
#define CURV    0.15f
#define EPS_F   1e-6f

typedef __attribute__((ext_vector_type(8))) short short8v;
typedef __attribute__((ext_vector_type(4))) float f32x4;

__device__ __forceinline__ void gl_lds16(const void* g, void* l) {
    __builtin_amdgcn_global_load_lds(
        (const __attribute__((address_space(1))) void*)g,
        (__attribute__((address_space(3))) void*)l, 16, 0, 0);
}
__device__ __forceinline__ unsigned short f2bf_bits(float x) {
    __hip_bfloat16 t = __float2bfloat16(x);
    return *(unsigned short*)&t;
}
__device__ __forceinline__ float bf2f(unsigned short u) {
    return __uint_as_float(((unsigned)u) << 16);
}

// ---------------------------------------------------------------------------
// cast fp32 -> bf16, 4 elems/thread
// ---------------------------------------------------------------------------
__global__ __launch_bounds__(256)
void cast_f32_bf16(const float* __restrict__ in, unsigned short* __restrict__ out,
                   int ngroups)
{
    int i = blockIdx.x * 256 + threadIdx.x;
    if (i >= ngroups) return;
    float4 u = ((const float4*)in)[i];
    ushort4 r;
    r.x = f2bf_bits(u.x); r.y = f2bf_bits(u.y);
    r.z = f2bf_bits(u.z); r.w = f2bf_bits(u.w);
    ((ushort4*)out)[i] = r;
}

// ---------------------------------------------------------------------------
// transpose + cast: W[K][N] fp32  ->  Wt[N][K] bf16.
// ---------------------------------------------------------------------------
__global__ __launch_bounds__(256)
void transpose_cast(const float* __restrict__ W, unsigned short* __restrict__ Wt,
                    int K, int N)
{
    __shared__ float tile[32][33];
    const int n0 = blockIdx.x * 32;
    const int k0 = blockIdx.y * 32;
    const int tx = threadIdx.x & 31;
    const int ty = threadIdx.x >> 5;
    #pragma unroll
    for (int i = 0; i < 32; i += 8)
        tile[ty + i][tx] = W[(size_t)(k0 + ty + i) * N + n0 + tx];
    __syncthreads();
    #pragma unroll
    for (int i = 0; i < 32; i += 8)
        Wt[(size_t)(n0 + ty + i) * K + k0 + tx] = f2bf_bits(tile[tx][ty + i]);
}

// ---------------------------------------------------------------------------
// 256x256 bf16 MFMA GEMM, fine-interleaved 4-phase/K-tile schedule.
// 512 threads = 8 waves (2M x 4N); BK=64; 128 KiB LDS double buffer; XOR
// swizzle via pre-swizzled source + swizzled ds_read (conflict-free, R3=0).
// Reads per phase: p0 a0-3+b01(12), p1 b23(4), p2 a4-7(8), p3 none.
// Stages: p2 -> B0,B1(T+2); p3 -> A0,A1(T+2)  (regions fully read by then:
//   B after p1's post-barrier, A after p2's post-barrier).
// Boundary: vmcnt(8) keeps exactly tile T+2's 8 gl_lds in flight.
// Barriers: post-phase only (4/tile) — pre-MFMA barriers carry no hazard.
// ---------------------------------------------------------------------------
template<int OUT_BF16>
__global__ __launch_bounds__(512, 2)
void gemm256_8ph(const unsigned short* __restrict__ A,
                 const unsigned short* __restrict__ Bt,
                 const float* __restrict__ bias,
                 void* __restrict__ Cout,
                 int M, int N, int K, int nbx)
{
    __shared__ __align__(16) short smem_s[65536];   // 128 KiB

    const int t    = threadIdx.x;
    const int w    = t >> 6;
    const int lane = t & 63;
    const int wm   = w >> 2;          // 0..1
    const int wn   = w & 3;           // 0..3
    const int lr   = lane & 15;
    const int hi   = lane >> 4;       // 0..3
    const int lo7  = lane & 7;

    // bijective XCD chunk swizzle (gridDim.x % 8 == 0)
    const int nwg  = gridDim.x;
    const int orig = blockIdx.x;
    const int wgid = (orig & 7) * (nwg >> 3) + (orig >> 3);
    const int by = wgid / nbx, bx = wgid % nbx;
    const int bm0 = by * 256, bn0 = bx * 256;

    const int nt = K >> 6;            // = 16 for K=1024

    // staging geometry: LDS dest linear, source col pre-swizzled (rule #21)
    const int srow = t >> 3;                        // 0..63
    const int scol = ((t & 7) ^ (srow & 7)) * 8;    // swizzled element col
    const unsigned short* Ag = A  + (size_t)(bm0 + srow) * K + scol;
    const unsigned short* Bg = Bt + (size_t)(bn0 + srow) * K + scol;
    const int wbase = w * 1024;                     // wave's byte base in half

    auto STAGE = [&](int which, int half, int tile) {
        const unsigned short* g0 = (which ? Bg : Ag)
                                 + (size_t)(half * 128) * K + (size_t)tile * 64;
        char* d0 = (char*)smem_s + ((tile & 1) * 65536 + which * 32768
                                    + half * 16384 + wbase);
        gl_lds16(g0,                d0);
        gl_lds16(g0 + (size_t)64*K, d0 + 8192);
    };

    short8v a[8][2], b[4][2];
    f32x4 acc[8][4] = {};

    auto LDA = [&](int buf, int m, int ks) {
        a[m][ks] = *(const short8v*)&smem_s[buf*32768 + wm*8192
                        + (m*16 + lr)*64 + (((ks*4 + hi) ^ lo7) * 8)];
    };
    auto LDB = [&](int buf, int n, int ks) {
        b[n][ks] = *(const short8v*)&smem_s[buf*32768 + 16384 + (wn>>1)*8192
                        + ((wn&1)*64 + n*16 + lr)*64 + (((ks*4 + hi) ^ lo7) * 8)];
    };
    auto QUAD = [&](int mlo, int nlo) {
        __builtin_amdgcn_s_setprio(1);
        #pragma unroll
        for (int mi = 0; mi < 4; ++mi)
            #pragma unroll
            for (int ni = 0; ni < 2; ++ni)
                #pragma unroll
                for (int ks = 0; ks < 2; ++ks)
                    acc[mlo+mi][nlo+ni] = __builtin_amdgcn_mfma_f32_16x16x32_bf16(
                        a[mlo+mi][ks], b[nlo+ni][ks], acc[mlo+mi][nlo+ni], 0, 0, 0);
        __builtin_amdgcn_s_setprio(0);
    };

    // ---- prologue: stage tiles 0 and 1 fully (16 gl_lds); wait tile 0 ----
    STAGE(0,0,0); STAGE(0,1,0); STAGE(1,0,0); STAGE(1,1,0);
    STAGE(0,0,1); STAGE(0,1,1); STAGE(1,0,1); STAGE(1,1,1);
    asm volatile("s_waitcnt vmcnt(8)" ::: "memory");   // tile 0 resident
    __builtin_amdgcn_s_barrier();

    for (int T = 0; T < nt; ++T) {
        const int buf = T & 1;
        // ---- phase 0: read a0-3 + b01; MFMA Q(m0-3, n0-1) ----
        #pragma unroll
        for (int m = 0; m < 4; ++m) { LDA(buf,m,0); LDA(buf,m,1); }
        LDB(buf,0,0); LDB(buf,0,1); LDB(buf,1,0); LDB(buf,1,1);
        asm volatile("s_waitcnt lgkmcnt(0)" ::: "memory");
        __builtin_amdgcn_sched_barrier(0);
        QUAD(0,0);
        __builtin_amdgcn_s_barrier();
        // ---- phase 1: read b23; MFMA Q(m0-3, n2-3) ----
        LDB(buf,2,0); LDB(buf,2,1); LDB(buf,3,0); LDB(buf,3,1);
        asm volatile("s_waitcnt lgkmcnt(0)" ::: "memory");
        __builtin_amdgcn_sched_barrier(0);
        QUAD(0,2);
        __builtin_amdgcn_s_barrier();        // <- all B-region reads complete
        // ---- phase 2: read a4-7; stage B0,B1(T+2); MFMA Q(m4-7, n0-1) ----
        #pragma unroll
        for (int m = 4; m < 8; ++m) { LDA(buf,m,0); LDA(buf,m,1); }
        if (T+2 < nt) { STAGE(1,0,T+2); STAGE(1,1,T+2); }
        asm volatile("s_waitcnt lgkmcnt(0)" ::: "memory");
        __builtin_amdgcn_sched_barrier(0);
        QUAD(4,0);
        __builtin_amdgcn_s_barrier();        // <- all A-region reads complete
        // ---- phase 3: stage A0,A1(T+2); MFMA Q(m4-7, n2-3); boundary ----
        if (T+2 < nt) { STAGE(0,0,T+2); STAGE(0,1,T+2); }
        QUAD(4,2);
        if (T+2 < nt) { asm volatile("s_waitcnt vmcnt(8)" ::: "memory"); }
        else          { asm volatile("s_waitcnt vmcnt(0)" ::: "memory"); }
        __builtin_amdgcn_s_barrier();        // <- buffer flip
    }

    // ---- epilogue: C/D layout col=lane&15, row=hi*4+j ----
    const int r0 = bm0 + wm*128 + hi*4;
    const int cb = bn0 + wn*64 + lr;
    float bv[4];
    #pragma unroll
    for (int n = 0; n < 4; ++n) bv[n] = bias[cb + n*16];
    if (OUT_BF16) {
        unsigned short* Cb = (unsigned short*)Cout;
        #pragma unroll
        for (int m = 0; m < 8; ++m)
            #pragma unroll
            for (int j = 0; j < 4; ++j) {
                unsigned short* rp = Cb + (size_t)(r0 + m*16 + j) * N;
                #pragma unroll
                for (int n = 0; n < 4; ++n)
                    rp[cb + n*16] = f2bf_bits(acc[m][n][j] + bv[n]);
            }
    } else {
        float* Cf = (float*)Cout;
        #pragma unroll
        for (int m = 0; m < 8; ++m)
            #pragma unroll
            for (int j = 0; j < 4; ++j) {
                float* rp = Cf + (size_t)(r0 + m*16 + j) * N;
                #pragma unroll
                for (int n = 0; n < 4; ++n)
                    rp[cb + n*16] = acc[m][n][j] + bv[n];
            }
    }
}

// ---------------------------------------------------------------------------
// Per-position head attention (bf16 in, bf16 out). One block per position.
// qkv row layout: [3][16][64]. thread t = (h,g) pair. fp32 internal math.
// ---------------------------------------------------------------------------
__global__ __launch_bounds__(256)
void attn_heads_kernel(const unsigned short* __restrict__ qkv,
                       unsigned short* __restrict__ aout)
{
    __shared__ float qs[16][68], ks[16][68], vs[16][68];
    __shared__ float qsq[16], ksq[16];
    __shared__ float attn_s[16][17];

    const int p = blockIdx.x;
    const int t = threadIdx.x;
    const short8v* rowv = (const short8v*)(qkv + (size_t)p * N_QKV);

    // stage+convert: 384 chunks of 8 bf16
    for (int c = t; c < N_QKV / 8; c += 256) {
        short8v v = rowv[c];
        int e0  = c << 3;
        int sec = e0 >> 10;
        int h   = (e0 >> 6) & 15;
        int d   = e0 & 63;
        float* dst = (sec == 0) ? &qs[h][d] : (sec == 1) ? &ks[h][d] : &vs[h][d];
        #pragma unroll
        for (int i = 0; i < 8; ++i)
            dst[i] = bf2f((unsigned short)v[i]);
    }
    __syncthreads();

    if (t < 32) {
        int hh = t & 15;
        const float* src = (t < 16) ? qs[hh] : ks[hh];
        float s = 0.f;
        #pragma unroll
        for (int d0 = 0; d0 < 64; d0 += 4) {
            float4 u = *(const float4*)(src + d0);
            s = fmaf(u.x,u.x, fmaf(u.y,u.y, fmaf(u.z,u.z, fmaf(u.w,u.w, s))));
        }
        if (t < 16) qsq[hh] = s; else ksq[hh] = s;
    }

    const int h = t >> 4;
    const int g = t & 15;
    float dot = 0.f;
    {
        const float* qr = qs[h];
        const float* kr = ks[g];
        #pragma unroll
        for (int d0 = 0; d0 < 64; d0 += 4) {
            float4 a = *(const float4*)(qr + d0);
            float4 b = *(const float4*)(kr + d0);
            dot = fmaf(a.x,b.x, fmaf(a.y,b.y, fmaf(a.z,b.z, fmaf(a.w,b.w, dot))));
        }
    }
    __syncthreads();

    float dsq = fmaxf(qsq[h] + ksq[g] - 2.f * dot, 0.f);
    dsq = dsq * (1.f + CURV * cosf(sqrtf(dsq + EPS_F)));
    float force = sqrtf(qsq[h]) * sqrtf(ksq[g]) / (dsq + EPS_F);

    float m = force;
    #pragma unroll
    for (int off = 8; off >= 1; off >>= 1)
        m = fmaxf(m, __shfl_xor(m, off, 16));
    float e = expf(force - m);
    float ssum = e;
    #pragma unroll
    for (int off = 8; off >= 1; off >>= 1)
        ssum += __shfl_xor(ssum, off, 16);
    attn_s[h][g] = e / ssum;
    __syncthreads();

    const int d  = t & 63;
    const int hb = t >> 6;
    float o[4] = {0.f, 0.f, 0.f, 0.f};
    #pragma unroll
    for (int gg = 0; gg < 16; ++gg) {
        float vv = vs[gg][d];
        #pragma unroll
        for (int hh = 0; hh < 4; ++hh)
            o[hh] = fmaf(attn_s[hb + hh*4][gg], vv, o[hh]);
    }
    unsigned short* orow = aout + (size_t)p * D_MODEL;
    #pragma unroll
    for (int hh = 0; hh < 4; ++hh)
        orow[(hb + hh*4) * 64 + d] = f2bf_bits(o[hh]);
}

// ---------------------------------------------------------------------------
extern "C" void kernel_launch(void* const* d_in, const int* in_sizes, int n_in,
                              void* d_out, int out_size, void* d_ws, size_t ws_size,
                              hipStream_t stream)
{
    const float* x     = (const float*)d_in[0];   // 16384 x 1024
    const float* W_qkv = (const float*)d_in[1];   // 1024 x 3072
    const float* b_qkv = (const float*)d_in[2];   // 3072
    const float* W_out = (const float*)d_in[3];   // 1024 x 1024
    const float* b_out = (const float*)d_in[4];   // 1024
    float* out = (float*)d_out;                   // 16384 x 1024

    // workspace: [0,96M) qkv bf16 | [96M,128M) xb/ab bf16 | Wt1 6M | Wt2 2M
    char* ws = (char*)d_ws;
    unsigned short* qkvb = (unsigned short*)ws;
    unsigned short* xb   = (unsigned short*)(ws + (size_t)M_TOTAL * N_QKV * 2);
    unsigned short* ab   = xb;   // alias: xb dead after GEMM1
    unsigned short* Wt1  = (unsigned short*)(ws + (size_t)M_TOTAL * N_QKV * 2
                                                + (size_t)M_TOTAL * D_MODEL * 2);
    unsigned short* Wt2  = Wt1 + (size_t)N_QKV * D_MODEL;

    // 0a) cast x -> bf16
    {
        int ngroups = M_TOTAL * D_MODEL / 4;
        cast_f32_bf16<<<ngroups / 256, 256, 0, stream>>>(x, xb, ngroups);
    }
    // 0b) transpose+cast weights
    {
        dim3 g(N_QKV / 32, D_MODEL / 32);
        transpose_cast<<<g, 256, 0, stream>>>(W_qkv, Wt1, D_MODEL, N_QKV);
        dim3 g2(D_MODEL / 32, D_MODEL / 32);
        transpose_cast<<<g2, 256, 0, stream>>>(W_out, Wt2, D_MODEL, D_MODEL);
    }

    // 1) qkv = x @ W_qkv + b_qkv  (bf16 out)
    {
        int nbx = N_QKV / 256;                 // 12
        int nwg = (M_TOTAL / 256) * nbx;       // 768 (%8==0)
        gemm256_8ph<1><<<nwg, 512, 0, stream>>>(xb, Wt1, b_qkv, qkvb,
                                                M_TOTAL, N_QKV, D_MODEL, nbx);
    }

    // 2) per-position head attention (bf16 -> bf16)
    attn_heads_kernel<<<M_TOTAL, 256, 0, stream>>>(qkvb, ab);

    // 3) out = ab @ W_out + b_out  (fp32 out)
    {
        int nbx = D_MODEL / 256;               // 4
        int nwg = (M_TOTAL / 256) * nbx;       // 256 (%8==0)
        gemm256_8ph<0><<<nwg, 512, 0, stream>>>(ab, Wt2, b_out, out,
                                                M_TOTAL, D_MODEL, D_MODEL, nbx);
    }
}

// Round 5
// 221.428 us; speedup vs baseline: 7.1907x; 1.0055x over previous
//
#include <hip/hip_runtime.h>
#include <hip/hip_bf16.h>
#include <math.h>

#define M_TOTAL 16384   // B*S = 4*4096
#define D_MODEL 1024
#define N_QKV   3072
#define CURV    0.15f
#define EPS_F   1e-6f

typedef __attribute__((ext_vector_type(8))) short short8v;
typedef __attribute__((ext_vector_type(4))) float f32x4;

__device__ __forceinline__ void gl_lds16(const void* g, void* l) {
    __builtin_amdgcn_global_load_lds(
        (const __attribute__((address_space(1))) void*)g,
        (__attribute__((address_space(3))) void*)l, 16, 0, 0);
}
__device__ __forceinline__ unsigned short f2bf_bits(float x) {
    __hip_bfloat16 t = __float2bfloat16(x);
    return *(unsigned short*)&t;
}
__device__ __forceinline__ float bf2f(unsigned short u) {
    return __uint_as_float(((unsigned)u) << 16);
}

// ---------------------------------------------------------------------------
// cast fp32 -> bf16, 4 elems/thread
// ---------------------------------------------------------------------------
__global__ __launch_bounds__(256)
void cast_f32_bf16(const float* __restrict__ in, unsigned short* __restrict__ out,
                   int ngroups)
{
    int i = blockIdx.x * 256 + threadIdx.x;
    if (i >= ngroups) return;
    float4 u = ((const float4*)in)[i];
    ushort4 r;
    r.x = f2bf_bits(u.x); r.y = f2bf_bits(u.y);
    r.z = f2bf_bits(u.z); r.w = f2bf_bits(u.w);
    ((ushort4*)out)[i] = r;
}

// ---------------------------------------------------------------------------
// transpose + cast: W[K][N] fp32  ->  Wt[N][K] bf16.
// ---------------------------------------------------------------------------
__global__ __launch_bounds__(256)
void transpose_cast(const float* __restrict__ W, unsigned short* __restrict__ Wt,
                    int K, int N)
{
    __shared__ float tile[32][33];
    const int n0 = blockIdx.x * 32;
    const int k0 = blockIdx.y * 32;
    const int tx = threadIdx.x & 31;
    const int ty = threadIdx.x >> 5;
    #pragma unroll
    for (int i = 0; i < 32; i += 8)
        tile[ty + i][tx] = W[(size_t)(k0 + ty + i) * N + n0 + tx];
    __syncthreads();
    #pragma unroll
    for (int i = 0; i < 32; i += 8)
        Wt[(size_t)(n0 + ty + i) * K + k0 + tx] = f2bf_bits(tile[tx][ty + i]);
}

// ---------------------------------------------------------------------------
// 256x256 bf16 MFMA GEMM — register-pipelined 4-phase/K-tile schedule.
// 512 thr = 8 waves (2Mx4N); BK=64; 128 KiB LDS dbuf; XOR swizzle (conflict-
// free, verified 0 in R3/R4). Quad q's frags are issued one phase EARLY and
// waited with COUNTED lgkmcnt, so each 16-MFMA burst covers the next reads:
//   p0: issue b23        -> lgkm(4) -> Q(0,0)
//   p1: issue a4-7       -> lgkm(8) -> Q(0,2) -> bar1 -> STAGE B(T+2)
//   p2:                     lgkm(0) -> Q(4,0) -> bar2 -> STAGE A(T+2)
//   p3: vmcnt(8)+bar3 -> issue T+1 frags (buf^1) -> Q(4,2)
// Hazards: every region's reads are consumed by an MFMA BEFORE the barrier
// gating its overwrite; vmcnt(8) (8 = T+2's in-flight gl_lds) retires T+1;
// tail uses vmcnt(0). DS reads retire in-order (all ds_read_b128).
// ---------------------------------------------------------------------------
template<int OUT_BF16>
__global__ __launch_bounds__(512, 2)
void gemm256_8ph(const unsigned short* __restrict__ A,
                 const unsigned short* __restrict__ Bt,
                 const float* __restrict__ bias,
                 void* __restrict__ Cout,
                 int M, int N, int K, int nbx)
{
    __shared__ __align__(16) short smem_s[65536];   // 128 KiB

    const int t    = threadIdx.x;
    const int w    = t >> 6;
    const int lane = t & 63;
    const int wm   = w >> 2;          // 0..1
    const int wn   = w & 3;           // 0..3
    const int lr   = lane & 15;
    const int hi   = lane >> 4;       // 0..3
    const int lo7  = lane & 7;

    // bijective XCD chunk swizzle (gridDim.x % 8 == 0)
    const int nwg  = gridDim.x;
    const int orig = blockIdx.x;
    const int wgid = (orig & 7) * (nwg >> 3) + (orig >> 3);
    const int by = wgid / nbx, bx = wgid % nbx;
    const int bm0 = by * 256, bn0 = bx * 256;

    const int nt = K >> 6;            // = 16 for K=1024

    // staging geometry: LDS dest linear, source col pre-swizzled (rule #21)
    const int srow = t >> 3;                        // 0..63
    const int scol = ((t & 7) ^ (srow & 7)) * 8;    // swizzled element col
    const unsigned short* Ag = A  + (size_t)(bm0 + srow) * K + scol;
    const unsigned short* Bg = Bt + (size_t)(bn0 + srow) * K + scol;
    const int wbase = w * 1024;                     // wave's byte base in half

    auto STAGE = [&](int which, int half, int tile) {
        const unsigned short* g0 = (which ? Bg : Ag)
                                 + (size_t)(half * 128) * K + (size_t)tile * 64;
        char* d0 = (char*)smem_s + ((tile & 1) * 65536 + which * 32768
                                    + half * 16384 + wbase);
        gl_lds16(g0,                d0);
        gl_lds16(g0 + (size_t)64*K, d0 + 8192);
    };

    short8v a[8][2], b[4][2];
    f32x4 acc[8][4] = {};

    auto LDA = [&](int buf, int m, int ks) {
        a[m][ks] = *(const short8v*)&smem_s[buf*32768 + wm*8192
                        + (m*16 + lr)*64 + (((ks*4 + hi) ^ lo7) * 8)];
    };
    auto LDB = [&](int buf, int n, int ks) {
        b[n][ks] = *(const short8v*)&smem_s[buf*32768 + 16384 + (wn>>1)*8192
                        + ((wn&1)*64 + n*16 + lr)*64 + (((ks*4 + hi) ^ lo7) * 8)];
    };
    auto QUAD = [&](int mlo, int nlo) {
        __builtin_amdgcn_s_setprio(1);
        #pragma unroll
        for (int mi = 0; mi < 4; ++mi)
            #pragma unroll
            for (int ni = 0; ni < 2; ++ni)
                #pragma unroll
                for (int ks = 0; ks < 2; ++ks)
                    acc[mlo+mi][nlo+ni] = __builtin_amdgcn_mfma_f32_16x16x32_bf16(
                        a[mlo+mi][ks], b[nlo+ni][ks], acc[mlo+mi][nlo+ni], 0, 0, 0);
        __builtin_amdgcn_s_setprio(0);
    };

    // ---- prologue: stage tiles 0,1 (16 gl_lds); tile0 resident; preload
    //      tile0's a0-3 + b01 fragments (12 ds_reads, waited in p0).
    STAGE(0,0,0); STAGE(0,1,0); STAGE(1,0,0); STAGE(1,1,0);
    STAGE(0,0,1); STAGE(0,1,1); STAGE(1,0,1); STAGE(1,1,1);
    asm volatile("s_waitcnt vmcnt(8)" ::: "memory");   // tile 0 resident
    __builtin_amdgcn_s_barrier();
    #pragma unroll
    for (int m = 0; m < 4; ++m) { LDA(0,m,0); LDA(0,m,1); }
    LDB(0,0,0); LDB(0,0,1); LDB(0,1,0); LDB(0,1,1);

    for (int T = 0; T < nt; ++T) {
        const int buf  = T & 1;
        const int nbuf = buf ^ 1;
        // ---- phase 0: issue b23; wait frags(12) via counted lgkm; Q(0,0) ----
        LDB(buf,2,0); LDB(buf,2,1); LDB(buf,3,0); LDB(buf,3,1);
        asm volatile("s_waitcnt lgkmcnt(4)" ::: "memory");
        __builtin_amdgcn_sched_barrier(0);
        QUAD(0,0);
        // ---- phase 1: issue a4-7; wait b23; Q(0,2); bar1; stage B(T+2) ----
        #pragma unroll
        for (int m = 4; m < 8; ++m) { LDA(buf,m,0); LDA(buf,m,1); }
        asm volatile("s_waitcnt lgkmcnt(8)" ::: "memory");
        __builtin_amdgcn_sched_barrier(0);
        QUAD(0,2);
        __builtin_amdgcn_s_barrier();        // all buf.B reads retired
        if (T+2 < nt) { STAGE(1,0,T+2); STAGE(1,1,T+2); }
        // ---- phase 2: wait a4-7; Q(4,0); bar2; stage A(T+2) ----
        asm volatile("s_waitcnt lgkmcnt(0)" ::: "memory");
        __builtin_amdgcn_sched_barrier(0);
        QUAD(4,0);
        __builtin_amdgcn_s_barrier();        // all buf.A reads retired
        if (T+2 < nt) { STAGE(0,0,T+2); STAGE(0,1,T+2); }
        // ---- phase 3: T+1 resident gate; issue T+1 frags; Q(4,2) ----
        if (T+2 < nt) { asm volatile("s_waitcnt vmcnt(8)" ::: "memory"); }
        else          { asm volatile("s_waitcnt vmcnt(0)" ::: "memory"); }
        __builtin_amdgcn_s_barrier();        // buf^1 (tile T+1) safe to read
        if (T+1 < nt) {
            #pragma unroll
            for (int m = 0; m < 4; ++m) { LDA(nbuf,m,0); LDA(nbuf,m,1); }
            LDB(nbuf,0,0); LDB(nbuf,0,1); LDB(nbuf,1,0); LDB(nbuf,1,1);
        }
        __builtin_amdgcn_sched_barrier(0);   // pin: reads issue before Q(4,2)
        QUAD(4,2);
    }

    // ---- epilogue: C/D layout col=lane&15, row=hi*4+j ----
    const int r0 = bm0 + wm*128 + hi*4;
    const int cb = bn0 + wn*64 + lr;
    float bv[4];
    #pragma unroll
    for (int n = 0; n < 4; ++n) bv[n] = bias[cb + n*16];
    if (OUT_BF16) {
        unsigned short* Cb = (unsigned short*)Cout;
        #pragma unroll
        for (int m = 0; m < 8; ++m)
            #pragma unroll
            for (int j = 0; j < 4; ++j) {
                unsigned short* rp = Cb + (size_t)(r0 + m*16 + j) * N;
                #pragma unroll
                for (int n = 0; n < 4; ++n)
                    rp[cb + n*16] = f2bf_bits(acc[m][n][j] + bv[n]);
            }
    } else {
        float* Cf = (float*)Cout;
        #pragma unroll
        for (int m = 0; m < 8; ++m)
            #pragma unroll
            for (int j = 0; j < 4; ++j) {
                float* rp = Cf + (size_t)(r0 + m*16 + j) * N;
                #pragma unroll
                for (int n = 0; n < 4; ++n)
                    rp[cb + n*16] = acc[m][n][j] + bv[n];
            }
    }
}

// ---------------------------------------------------------------------------
// Per-position head attention (bf16 in, bf16 out). One block per position.
// qkv row layout: [3][16][64]. thread t = (h,g) pair. fp32 internal math.
// ---------------------------------------------------------------------------
__global__ __launch_bounds__(256)
void attn_heads_kernel(const unsigned short* __restrict__ qkv,
                       unsigned short* __restrict__ aout)
{
    __shared__ float qs[16][68], ks[16][68], vs[16][68];
    __shared__ float qsq[16], ksq[16];
    __shared__ float attn_s[16][17];

    const int p = blockIdx.x;
    const int t = threadIdx.x;
    const short8v* rowv = (const short8v*)(qkv + (size_t)p * N_QKV);

    // stage+convert: 384 chunks of 8 bf16
    for (int c = t; c < N_QKV / 8; c += 256) {
        short8v v = rowv[c];
        int e0  = c << 3;
        int sec = e0 >> 10;
        int h   = (e0 >> 6) & 15;
        int d   = e0 & 63;
        float* dst = (sec == 0) ? &qs[h][d] : (sec == 1) ? &ks[h][d] : &vs[h][d];
        #pragma unroll
        for (int i = 0; i < 8; ++i)
            dst[i] = bf2f((unsigned short)v[i]);
    }
    __syncthreads();

    if (t < 32) {
        int hh = t & 15;
        const float* src = (t < 16) ? qs[hh] : ks[hh];
        float s = 0.f;
        #pragma unroll
        for (int d0 = 0; d0 < 64; d0 += 4) {
            float4 u = *(const float4*)(src + d0);
            s = fmaf(u.x,u.x, fmaf(u.y,u.y, fmaf(u.z,u.z, fmaf(u.w,u.w, s))));
        }
        if (t < 16) qsq[hh] = s; else ksq[hh] = s;
    }

    const int h = t >> 4;
    const int g = t & 15;
    float dot = 0.f;
    {
        const float* qr = qs[h];
        const float* kr = ks[g];
        #pragma unroll
        for (int d0 = 0; d0 < 64; d0 += 4) {
            float4 a = *(const float4*)(qr + d0);
            float4 b = *(const float4*)(kr + d0);
            dot = fmaf(a.x,b.x, fmaf(a.y,b.y, fmaf(a.z,b.z, fmaf(a.w,b.w, dot))));
        }
    }
    __syncthreads();

    float dsq = fmaxf(qsq[h] + ksq[g] - 2.f * dot, 0.f);
    dsq = dsq * (1.f + CURV * cosf(sqrtf(dsq + EPS_F)));
    float force = sqrtf(qsq[h]) * sqrtf(ksq[g]) / (dsq + EPS_F);

    float m = force;
    #pragma unroll
    for (int off = 8; off >= 1; off >>= 1)
        m = fmaxf(m, __shfl_xor(m, off, 16));
    float e = expf(force - m);
    float ssum = e;
    #pragma unroll
    for (int off = 8; off >= 1; off >>= 1)
        ssum += __shfl_xor(ssum, off, 16);
    attn_s[h][g] = e / ssum;
    __syncthreads();

    const int d  = t & 63;
    const int hb = t >> 6;
    float o[4] = {0.f, 0.f, 0.f, 0.f};
    #pragma unroll
    for (int gg = 0; gg < 16; ++gg) {
        float vv = vs[gg][d];
        #pragma unroll
        for (int hh = 0; hh < 4; ++hh)
            o[hh] = fmaf(attn_s[hb + hh*4][gg], vv, o[hh]);
    }
    unsigned short* orow = aout + (size_t)p * D_MODEL;
    #pragma unroll
    for (int hh = 0; hh < 4; ++hh)
        orow[(hb + hh*4) * 64 + d] = f2bf_bits(o[hh]);
}

// ---------------------------------------------------------------------------
extern "C" void kernel_launch(void* const* d_in, const int* in_sizes, int n_in,
                              void* d_out, int out_size, void* d_ws, size_t ws_size,
                              hipStream_t stream)
{
    const float* x     = (const float*)d_in[0];   // 16384 x 1024
    const float* W_qkv = (const float*)d_in[1];   // 1024 x 3072
    const float* b_qkv = (const float*)d_in[2];   // 3072
    const float* W_out = (const float*)d_in[3];   // 1024 x 1024
    const float* b_out = (const float*)d_in[4];   // 1024
    float* out = (float*)d_out;                   // 16384 x 1024

    // workspace: [0,96M) qkv bf16 | [96M,128M) xb/ab bf16 | Wt1 6M | Wt2 2M
    char* ws = (char*)d_ws;
    unsigned short* qkvb = (unsigned short*)ws;
    unsigned short* xb   = (unsigned short*)(ws + (size_t)M_TOTAL * N_QKV * 2);
    unsigned short* ab   = xb;   // alias: xb dead after GEMM1
    unsigned short* Wt1  = (unsigned short*)(ws + (size_t)M_TOTAL * N_QKV * 2
                                                + (size_t)M_TOTAL * D_MODEL * 2);
    unsigned short* Wt2  = Wt1 + (size_t)N_QKV * D_MODEL;

    // 0a) cast x -> bf16
    {
        int ngroups = M_TOTAL * D_MODEL / 4;
        cast_f32_bf16<<<ngroups / 256, 256, 0, stream>>>(x, xb, ngroups);
    }
    // 0b) transpose+cast weights
    {
        dim3 g(N_QKV / 32, D_MODEL / 32);
        transpose_cast<<<g, 256, 0, stream>>>(W_qkv, Wt1, D_MODEL, N_QKV);
        dim3 g2(D_MODEL / 32, D_MODEL / 32);
        transpose_cast<<<g2, 256, 0, stream>>>(W_out, Wt2, D_MODEL, D_MODEL);
    }

    // 1) qkv = x @ W_qkv + b_qkv  (bf16 out)
    {
        int nbx = N_QKV / 256;                 // 12
        int nwg = (M_TOTAL / 256) * nbx;       // 768 (%8==0)
        gemm256_8ph<1><<<nwg, 512, 0, stream>>>(xb, Wt1, b_qkv, qkvb,
                                                M_TOTAL, N_QKV, D_MODEL, nbx);
    }

    // 2) per-position head attention (bf16 -> bf16)
    attn_heads_kernel<<<M_TOTAL, 256, 0, stream>>>(qkvb, ab);

    // 3) out = ab @ W_out + b_out  (fp32 out)
    {
        int nbx = D_MODEL / 256;               // 4
        int nwg = (M_TOTAL / 256) * nbx;       // 256 (%8==0)
        gemm256_8ph<0><<<nwg, 512, 0, stream>>>(ab, Wt2, b_out, out,
                                                M_TOTAL, D_MODEL, D_MODEL, nbx);
    }
}